// Round 9
// baseline (180.496 us; speedup 1.0000x reference)
//
#include <hip/hip_runtime.h>
#include <hip/hip_bf16.h>
#include <math.h>

#define NB 2
#define NC 256
#define HWIN 4096
#define NN 4096
#define ND 32
#define NHH 4
#define EPSV 1e-5f

typedef short short8 __attribute__((ext_vector_type(8)));
typedef float f32x4 __attribute__((ext_vector_type(4)));
typedef unsigned short u16;
typedef unsigned int u32;

// workspace offsets (float32 units)
#define OFF_T1   0          // 131072  (t1T: [b][s][c], c-contiguous)
#define OFF_T2   262144     // 524288  (t2T: [b][s][c])
#define OFF_Q    1310720    // 524288 (bf16 x 1048576)
#define OFF_KT1  1835008    // 65536
#define OFF_VT1  1900544    // 65536
#define OFF_KT2  1966080    // 262144
#define OFF_VT2  2228224    // 262144
#define OFF_RCT1 2490368    // 40960
#define OFF_RCT2 2531328    // 163840
#define OFF_WT   2695168    // 131072  (kvw packed: wtp[c4][o][4], f32)
#define OFF_QWT  5054464    // 32768   (qw packed: qwp2[c][ocq][4], f32)
#define OFF_LWP  5087232    // 2304    (lw packed: lwp[tap][c], f32)
// end 5089536 floats = 20.4 MB

#define QSCALE 0.2550437314857726f   // 1/sqrt(32) * log2(e)
#define LOG2E  1.4426950408889634f

__device__ __forceinline__ u16 f2bf(float x) {   // f32 -> bf16 RNE
  unsigned u = __float_as_uint(x);
  u += 0x7fffu + ((u >> 16) & 1u);
  return (u16)(u >> 16);
}

__device__ __forceinline__ u32 pk_bf16(float a, float b) {  // packed RNE cvt
  __hip_bfloat162 h = __float22bfloat162_rn(make_float2(a, b));
  u32 r; __builtin_memcpy(&r, &h, 4);
  return r;
}

__device__ __forceinline__ float keysw(float t) {  // Keys cubic, a=-0.5
  t = fabsf(t);
  float w;
  if (t < 1.f)       w = ((1.5f*t - 2.5f)*t)*t + 1.f;
  else if (t < 2.f)  w = ((-0.5f*t + 2.5f)*t - 4.f)*t + 2.f;
  else               w = 0.f;
  return w;
}

// ---------- device bodies ----------
// dwconv stores SPATIAL-MAJOR: tT[b][s][c] (stage-2 loads lane-over-c f32x4).
template<int KS, int STR, int PAD, int OH>
__device__ __forceinline__ void dwconv_body(int idx, const float* __restrict__ x,
    const float* __restrict__ dww, const float* __restrict__ bn1,
    const float* __restrict__ pww, const float* __restrict__ bn2,
    float* __restrict__ tout) {
  const int hw = OH*OH;
  int s = idx % hw; int c = (idx/hw) % NC; int b = idx/(hw*NC);
  int oy = s / OH, ox = s % OH;
  const float* xp = x + (b*NC + c)*HWIN;
  const float* wp = dww + c*KS*KS;
  float acc = 0.f;
  #pragma unroll
  for (int ky = 0; ky < KS; ++ky) {
    int iy = oy*STR - PAD + ky;
    if (iy < 0 || iy >= 64) continue;
    #pragma unroll
    for (int kx = 0; kx < KS; ++kx) {
      int ix = ox*STR - PAD + kx;
      if (ix < 0 || ix >= 64) continue;
      acc += xp[iy*64 + ix] * wp[ky*KS + kx];
    }
  }
  float s1 = bn1[c] * rsqrtf(bn1[3*NC + c] + EPSV);
  float z = (acc - bn1[2*NC + c])*s1 + bn1[NC + c];
  z = fmaxf(z, 0.f);
  float s2 = bn2[c] * rsqrtf(bn2[3*NC + c] + EPSV);
  z = z * (pww[c]*s2) + (bn2[NC + c] - bn2[2*NC + c]*s2);
  tout[((size_t)(b*hw + s))*NC + c] = z;   // transposed store
}

__device__ __forceinline__ void rpe_body(int idx, const float* __restrict__ rpe,
                                         u16* __restrict__ rcT, int L, int ch) {
  int r = idx & 63; int l = (idx >> 6) % L; int b = idx / (64*L);
  float f = ((float)l + 0.5f)*(64.f/(float)L) - 0.5f;
  int i0 = (int)floorf(f) - 1;
  const float* rp = rpe + ((b*2 + ch)*64 + r)*64;
  float v = 0.f, wsum = 0.f;
  #pragma unroll
  for (int j = 0; j < 4; ++j) {
    int i = i0 + j;
    if (i >= 0 && i < 64) {
      float w = keysw(f - (float)i);
      v += w * rp[i]; wsum += w;
    }
  }
  rcT[((size_t)(b*L + l))*80 + 4 + r] = f2bf(v / wsum);
}

// ---------- stage 1: dwconvs (transposed out) + weight repacks ----------
// (rpe moved to localkv: rct* is consumed only by attn, so it can ride in
// localkv's spare scheduler slots instead of extending prep's tail.)
__global__ void __launch_bounds__(256) prep_kernel(
    const float* __restrict__ x,
    const float* __restrict__ dw1, const float* __restrict__ bn11,
    const float* __restrict__ pw1, const float* __restrict__ bn12, float* __restrict__ t1,
    const float* __restrict__ dw2, const float* __restrict__ bn21,
    const float* __restrict__ pw2, const float* __restrict__ bn22, float* __restrict__ t2,
    const float* __restrict__ kvw, float* __restrict__ wtp,
    const float* __restrict__ qw, float* __restrict__ qwp2,
    const float* __restrict__ lw, float* __restrict__ lwp) {
  int blk = blockIdx.x;
  int t = threadIdx.x;
  if (blk < 512) {
    dwconv_body<7,4,3,16>(blk*256 + t, x, dw1, bn11, pw1, bn12, t1);
  } else if (blk < 2560) {
    dwconv_body<5,2,2,32>((blk-512)*256 + t, x, dw2, bn21, pw2, bn22, t2);
  } else if (blk < 2688) {
    // kvw repack: wtp[(c4*512 + o)*4 + j] = kvw[o*256 + c4*4 + j]
    int idx = (blk-2560)*256 + t;          // 0..32767
    float4 vv = *(const float4*)(kvw + (size_t)idx*4);
    int o = idx >> 6, c4 = idx & 63;
    *(float4*)(wtp + ((size_t)(c4*512 + o))*4) = vv;
  } else if (blk < 2720) {
    // qw repack: qwp2[(c*32 + ocq)*4 + r] = qw[(ocq*4 + r)*256 + c]
    int idx = (blk-2688)*256 + t;          // 0..8191
    float4 vv = *(const float4*)(qw + (size_t)idx*4);
    int oc = idx >> 6, c0 = (idx & 63)*4;
    int ocq = oc >> 2, r = oc & 3;
    qwp2[((size_t)((c0+0)*32 + ocq))*4 + r] = vv.x;
    qwp2[((size_t)((c0+1)*32 + ocq))*4 + r] = vv.y;
    qwp2[((size_t)((c0+2)*32 + ocq))*4 + r] = vv.z;
    qwp2[((size_t)((c0+3)*32 + ocq))*4 + r] = vv.w;
  } else {
    // lw repack: lwp[tap*256 + c] = lw[c*9 + tap]
    int c = t;
    #pragma unroll
    for (int tp = 0; tp < 9; ++tp) lwp[tp*256 + c] = lw[c*9 + tp];
  }
}

// ---------- stage 2: fused local 3x3 + kv 1x1 + q 1x1 + rpe resample ----------
// 256-thr blocks, 16KB LDS.
// [0,640): strip tiles (8 spatial), PAIRED even=K/odd=V (dense tT loads).
// [640,896): q conv, 32 spatial, x staged in TWO 128-channel passes.
// [896,2176): rpe bicubic resample (moved from prep; outputs feed attn only).
__global__ void __launch_bounds__(256) localkv_kernel(
    const float* __restrict__ t1T, const float* __restrict__ t2T,
    const float* __restrict__ lwp, const float* __restrict__ lb,
    const float* __restrict__ wtp, const float* __restrict__ kvb,
    u16* __restrict__ kt1, u16* __restrict__ vt1,
    u16* __restrict__ kt2, u16* __restrict__ vt2,
    const float* __restrict__ x, const float* __restrict__ qwp2,
    const float* __restrict__ qb, u16* __restrict__ q,
    const float* __restrict__ rpe, u16* __restrict__ rct1, u16* __restrict__ rct2) {
  __shared__ float sbuf[128*32];   // 16KB
  int blk = blockIdx.x, tid = threadIdx.x;
  if (blk < 640) {
    int kv = blk & 1, ti = blk >> 1;          // 320 tiles of 8 spatial
    const float* tT; u16 *kT, *vT; int OH, hw, b, s0;
    if (ti < 64) { tT = t1T; kT = kt1; vT = vt1; OH = 16; hw = 256;  b = ti >> 5; s0 = (ti & 31)*8; }
    else { int v2 = ti-64; tT = t2T; kT = kt2; vT = vt2; OH = 32; hw = 1024; b = v2 >> 7; s0 = (v2 & 127)*8; }
    int oy = s0 / OH, ox0 = s0 % OH;
    const float* tb = tT + (size_t)b*hw*NC;
    // ---- stage A: 4 channels x 2 spatial per thread, dense f32x4 loads ----
    int cl = tid & 63, spg = tid >> 6;        // 64 c-quads x 4 sp-groups
    int c0 = cl*4;
    f32x4 wt9[9];
    #pragma unroll
    for (int tp = 0; tp < 9; ++tp) wt9[tp] = *(const f32x4*)(lwp + tp*256 + c0);
    f32x4 lb4 = *(const f32x4*)(lb + c0);
    #pragma unroll
    for (int i = 0; i < 2; ++i) {
      int sp = spg*2 + i;
      int ox = ox0 + sp;
      f32x4 a = lb4;
      #pragma unroll
      for (int dy = 0; dy < 3; ++dy) {
        int iy = oy + dy - 1;
        if (iy < 0 || iy >= OH) continue;
        #pragma unroll
        for (int dx = 0; dx < 3; ++dx) {
          int ix = ox + dx - 1;
          if (ix < 0 || ix >= OH) continue;
          f32x4 tv = *(const f32x4*)(tb + (size_t)(iy*OH + ix)*NC + c0);
          a += tv * wt9[dy*3 + dx];
        }
      }
      a += *(const f32x4*)(tb + (size_t)(oy*OH + ox)*NC + c0);   // residual
      *(f32x4*)(sbuf + sp*NC + c0) = a;                          // contiguous
    }
    __syncthreads();
    // ---- stage B: 2 outputs x 4 spatial per thread ----
    int ol = tid & 127, sph = tid >> 7;
    int o0i = kv*256 + ol, o1i = o0i + 128;
    float acc0[4], acc1[4];
    float b0 = kvb[o0i], b1 = kvb[o1i];
    #pragma unroll
    for (int i = 0; i < 4; ++i) { acc0[i] = b0; acc1[i] = b1; }
    #pragma unroll 2
    for (int c4 = 0; c4 < 64; ++c4) {
      f32x4 w0 = *(const f32x4*)(wtp + ((size_t)(c4*512 + o0i))*4);
      f32x4 w1 = *(const f32x4*)(wtp + ((size_t)(c4*512 + o1i))*4);
      #pragma unroll
      for (int i = 0; i < 4; ++i) {
        f32x4 y4 = *(const f32x4*)(sbuf + (sph*4 + i)*NC + c4*4);  // broadcast
        #pragma unroll
        for (int j = 0; j < 4; ++j) { acc0[i] += w0[j]*y4[j]; acc1[i] += w1[j]*y4[j]; }
      }
    }
    int L2 = 2*hw;
    #pragma unroll
    for (int k = 0; k < 2; ++k) {
      const float* ap = k ? acc1 : acc0;
      int oo = ol + k*128;                 // 0..255 within K-or-V half
      int hh = oo >> 6, r = oo & 63, d = r >> 1, e = r & 1;
      if (kv == 0) {
        u16* kp = kT + ((size_t)((b*NHH + hh)*L2 + e*hw + s0 + sph*4))*ND + d;
        #pragma unroll
        for (int j = 0; j < 4; ++j) kp[j*ND] = f2bf(ap[j]);
      } else {
        int l0v = e*hw + s0 + sph*4;
        u16* vp = vT + ((size_t)((b*NHH + hh)*(L2/64) + (l0v >> 6))*ND + d)*64 + (l0v & 63);
        #pragma unroll
        for (int j = 0; j < 4; ++j) vp[j] = f2bf(ap[j]);
      }
    }
  } else if (blk < 896) {
    // ---- q conv: 32 spatial/block, x staged in two 128-channel passes ----
    int qblk = blk - 640;                // 0..255
    int b = qblk >> 7;
    int n0 = (qblk & 127) * 32;
    const float* xb = x + (size_t)b*NC*HWIN + n0;
    int ocq = tid & 31, spg = tid >> 5;  // 32 oc-quads x 8 sp-groups
    float acc[4][4];
    #pragma unroll
    for (int k = 0; k < 4; ++k) {
      float bias = qb[ocq*4 + k];
      #pragma unroll
      for (int i = 0; i < 4; ++i) acc[k][i] = bias;
    }
    #pragma unroll
    for (int half = 0; half < 2; ++half) {
      #pragma unroll
      for (int j = 0; j < 4; ++j) {
        int u = tid + 256*j;             // f32x4 units over [128 c][8 groups]
        int c = u >> 3, spq = u & 7;
        *(f32x4*)(sbuf + c*32 + spq*4) =
            *(const f32x4*)(xb + (size_t)(half*128 + c)*HWIN + spq*4);
      }
      __syncthreads();
      #pragma unroll 4
      for (int c = 0; c < 128; ++c) {
        int cg = half*128 + c;
        f32x4 w4 = *(const f32x4*)(qwp2 + ((size_t)(cg*32 + ocq))*4);  // 4 oc
        f32x4 y4 = *(const f32x4*)(sbuf + c*32 + spg*4);               // 4 sp
        #pragma unroll
        for (int k = 0; k < 4; ++k)
          #pragma unroll
          for (int i = 0; i < 4; ++i) acc[k][i] += w4[k]*y4[i];
      }
      __syncthreads();
    }
    #pragma unroll
    for (int k = 0; k < 4; ++k) {
      int oc = ocq*4 + k;
      int h = oc >> 5, d = oc & 31;
      u16* qp = q + (((size_t)(b*NHH + h))*NN + n0 + spg*4)*ND + d;
      #pragma unroll
      for (int i = 0; i < 4; ++i) qp[i*ND] = f2bf(acc[k][i]*QSCALE);
    }
  } else if (blk < 1152) {
    rpe_body((blk-896)*256 + tid, rpe, rct1, 512, 0);
  } else {
    rpe_body((blk-1152)*256 + tid, rpe, rct2, 2048, 1);
  }
}

// ---------- stage 3: MFMA flash attention, both branches folded per block ----------
// Each block owns ONE (b,hh,rb) output row-group and runs TWO passes:
// pass 0 = branch1 (L=512, 8 tiles) -> out d-cols 0..31,
// pass 1 = branch2 (L=2048, 32 tiles) -> out d-cols 32..63.
// Rationale: both branches share the SAME Q (ref uses q[:, :4] for both) and
// the same per-row tap weights; folding removes the br1/br2 load-imbalance
// tail (512 uniform 40-tile blocks; per-CU tile work unchanged at 80) and
// halves Q loads + wtf setup. Arithmetic within each branch is unchanged.
__global__ void __launch_bounds__(256) attn_kernel(
    const u16* __restrict__ qbf,
    const u16* __restrict__ kt1, const u16* __restrict__ vt1, const u16* __restrict__ rct1,
    const u16* __restrict__ kt2, const u16* __restrict__ vt2, const u16* __restrict__ rct2,
    float* __restrict__ out) {
  __shared__ u16 kbuf[64*32];          // K tile, swizzled, 4KB
  __shared__ u16 vbuf[32*64];          // V tile, swizzled, 4KB
  __shared__ u32 pbuf_all[4][16*32];   // per-wave P^T tile, swizzled, 2KB/wave
  int u = blockIdx.x;                  // 512 blocks
  int b = u >> 8, hh = (u >> 6) & 3, rb = u & 63;
  int tid = threadIdx.x;
  int w = tid >> 6, lane = tid & 63;
  int g = lane >> 4, lo = lane & 15;
  u32* pbuf = pbuf_all[w];
  u16* pbuf16 = (u16*)pbuf;
  int n = rb*64 + w*16 + lo;

  // Q B-frag (shared by both branches; pre-scaled by 1/sqrt(32)*log2e)
  short8 qf = *(const short8*)(qbf + (((size_t)(b*NHH + hh))*NN + n)*ND + 8*g);

  // tap-weight B-frag for RPE ext-MFMA (row-dependent only; shared)
  float fr = ((float)n + 0.5f)*(1.f/64.f) - 0.5f;
  int ri0 = (int)floorf(fr) - 1;
  int a = (w < 2) ? rb - 2 : rb - 1;     // wave-uniform floor(fr(q0)) - 1
  int rmin = a & ~3;
  float wr4[4]; float wsum = 0.f;
  #pragma unroll
  for (int j = 0; j < 4; ++j) {
    int i = ri0 + j;
    float wv = (i >= 0 && i < 64) ? keysw(fr - (float)i) : 0.f;
    wr4[j] = wv; wsum += wv;
  }
  float invw = LOG2E / wsum;
  float wt8[8];
  #pragma unroll
  for (int s = 0; s < 8; ++s) {
    float acc = 0.f;
    #pragma unroll
    for (int j = 0; j < 4; ++j)
      acc += (ri0 + j - rmin == s) ? wr4[j]*invw : 0.f;
    wt8[s] = acc;
  }
  short8 wtf;
  {
    u32 p0 = pk_bf16(wt8[0], wt8[1]), p1 = pk_bf16(wt8[2], wt8[3]);
    u32 p2 = pk_bf16(wt8[4], wt8[5]), p3 = pk_bf16(wt8[6], wt8[7]);
    uint4 uu = make_uint4(p0, p1, p2, p3);
    wtf = __builtin_bit_cast(short8, uu);
    if (g != 0) wtf = (short8)0;
  }

  const f32x4 zero = {0.f, 0.f, 0.f, 0.f};

  // staging lane roles + swizzle constants (branch-independent)
  int kr_row = tid >> 2, kr_col = (tid & 3)*8;   // K: 64 rows x 32 u16
  int kr_sw  = ((kr_row >> 1) & 3)*8;
  int vr_row = tid >> 3, vr_col = (tid & 7)*8;   // V: 32 rows x 64 u16
  int vr_sw  = (vr_row & 7)*8;
  int ksw = ((lo >> 1) & 3)*8;
  int vsw = (lo & 7)*8;
  int psw4 = (lo & 7)*4;
  int psw8 = (lo & 7)*8;

  for (int pass = 0; pass < 2; ++pass) {
    const int L  = pass ? 2048 : 512;
    const int nt = pass ? 32 : 8;
    const u16* kbase  = (pass ? kt2 : kt1) + (size_t)(b*NHH + hh)*L*ND;
    const u16* vbase  = (pass ? vt2 : vt1) + (size_t)(b*NHH + hh)*ND*L;  // [L/64][32][64]
    const u16* rcrow0 = (pass ? rct2 : rct1) + (size_t)b*L*80 + (rmin + 4);

    auto stageLoad = [&](short8& kr, short8& vr, int l0) {
      kr = *(const short8*)(kbase + (size_t)(l0 + kr_row)*ND + kr_col);
      vr = *(const short8*)(vbase + (size_t)(l0 >> 6)*(ND*64) + vr_row*64 + vr_col);
    };
    auto stageStore = [&](short8 kr, short8 vr) {
      *(short8*)(kbuf + kr_row*32 + (kr_col ^ kr_sw)) = kr;
      *(short8*)(vbuf + vr_row*64 + (vr_col ^ vr_sw)) = vr;
    };
    auto loadRC = [&](uint4 (&rc)[4], int l0) {
      #pragma unroll
      for (int c = 0; c < 4; ++c) {
        const u16* arow = rcrow0 + (size_t)(l0 + 16*c + lo)*80;
        uint2 ra = *(const uint2*)arow;
        uint2 rb2 = *(const uint2*)(arow + 4);
        rc[c] = make_uint4(ra.x, ra.y, rb2.x, rb2.y);
      }
    };

    float ssum = 0.f;
    f32x4 o0 = zero, o1 = zero;
    short8 kr, vr;
    uint4 rcA[4], rcB[4];
    stageLoad(kr, vr, 0);
    loadRC(rcA, 0);

    for (int t = 0; t < nt; ++t) {
      stageStore(kr, vr);
      __syncthreads();
      if (t < nt-1) { stageLoad(kr, vr, (t+1)*64); loadRC(rcB, (t+1)*64); }
      f32x4 s4[4];
      #pragma unroll
      for (int c = 0; c < 4; ++c) {
        short8 rcf = __builtin_bit_cast(short8, rcA[c]);
        f32x4 accr = __builtin_amdgcn_mfma_f32_16x16x32_bf16(rcf, wtf, zero, 0, 0, 0);
        short8 kf = *(const short8*)(kbuf + (16*c + lo)*32 + ((8*g) ^ ksw));
        s4[c] = __builtin_amdgcn_mfma_f32_16x16x32_bf16(kf, qf, accr, 0, 0, 0);
      }
      float psum = 0.f;
      u32 pk[8];
      #pragma unroll
      for (int c = 0; c < 4; ++c) {
        float p0 = __builtin_amdgcn_exp2f(s4[c][0]);
        float p1 = __builtin_amdgcn_exp2f(s4[c][1]);
        float p2 = __builtin_amdgcn_exp2f(s4[c][2]);
        float p3 = __builtin_amdgcn_exp2f(s4[c][3]);
        psum += (p0 + p1) + (p2 + p3);
        pk[2*c]   = pk_bf16(p0, p1);
        pk[2*c+1] = pk_bf16(p2, p3);
      }
      ssum += psum;
      #pragma unroll
      for (int c = 0; c < 4; ++c)
        *(uint2*)(pbuf + lo*32 + ((8*c + 2*g) ^ psw4)) = make_uint2(pk[2*c], pk[2*c+1]);
      short8 pf0 = *(const short8*)(pbuf16 + lo*64 + ((8*g) ^ psw8));
      short8 pf1 = *(const short8*)(pbuf16 + lo*64 + ((32 + 8*g) ^ psw8));
      short8 v00 = *(const short8*)(vbuf + lo*64 + ((8*g) ^ vsw));
      short8 v01 = *(const short8*)(vbuf + lo*64 + ((32 + 8*g) ^ vsw));
      short8 v10 = *(const short8*)(vbuf + (16 + lo)*64 + ((8*g) ^ vsw));
      short8 v11 = *(const short8*)(vbuf + (16 + lo)*64 + ((32 + 8*g) ^ vsw));
      o0 = __builtin_amdgcn_mfma_f32_16x16x32_bf16(v00, pf0, o0, 0, 0, 0);
      o1 = __builtin_amdgcn_mfma_f32_16x16x32_bf16(v10, pf0, o1, 0, 0, 0);
      o0 = __builtin_amdgcn_mfma_f32_16x16x32_bf16(v01, pf1, o0, 0, 0, 0);
      o1 = __builtin_amdgcn_mfma_f32_16x16x32_bf16(v11, pf1, o1, 0, 0, 0);
      if (t < nt-1) {
        #pragma unroll
        for (int j = 0; j < 4; ++j) rcA[j] = rcB[j];
      }
      __syncthreads();   // all reads done before next tile's (or pass's) store
    }

    ssum += __shfl_xor(ssum, 16, 64);
    ssum += __shfl_xor(ssum, 32, 64);
    float inv = 1.f/ssum;
    f32x4 w0 = o0*inv, w1 = o1*inv;
    // pass0 (branch1) -> d-cols 0..31; pass1 (branch2) -> 32..63
    float* op = out + ((size_t)((b*NC + hh*64 + rb)*64 + (w*16 + lo)))*64 + pass*32;
    *(f32x4*)(op + 4*g)      = w0;
    *(f32x4*)(op + 16 + 4*g) = w1;
  }
}

extern "C" void kernel_launch(void* const* d_in, const int* in_sizes, int n_in,
                              void* d_out, int out_size, void* d_ws, size_t ws_size,
                              hipStream_t stream) {
  const float* x    = (const float*)d_in[0];
  const float* rpe  = (const float*)d_in[1];
  const float* qw   = (const float*)d_in[2];
  const float* qb   = (const float*)d_in[3];
  const float* kvw  = (const float*)d_in[4];
  const float* kvb  = (const float*)d_in[5];
  const float* dw1  = (const float*)d_in[6];
  const float* bn11 = (const float*)d_in[7];
  const float* pw1  = (const float*)d_in[8];
  const float* bn12 = (const float*)d_in[9];
  const float* dw2  = (const float*)d_in[10];
  const float* bn21 = (const float*)d_in[11];
  const float* pw2  = (const float*)d_in[12];
  const float* bn22 = (const float*)d_in[13];
  const float* lw   = (const float*)d_in[14];
  const float* lb   = (const float*)d_in[15];
  float* out = (float*)d_out;
  float* ws  = (float*)d_ws;

  float* t1   = ws + OFF_T1;
  float* t2   = ws + OFF_T2;
  u16*   q    = (u16*)(ws + OFF_Q);
  u16*   kt1  = (u16*)(ws + OFF_KT1);
  u16*   vt1  = (u16*)(ws + OFF_VT1);
  u16*   kt2  = (u16*)(ws + OFF_KT2);
  u16*   vt2  = (u16*)(ws + OFF_VT2);
  u16*   rct1 = (u16*)(ws + OFF_RCT1);
  u16*   rct2 = (u16*)(ws + OFF_RCT2);
  float* wtp  = ws + OFF_WT;
  float* qwp2 = ws + OFF_QWT;
  float* lwp  = ws + OFF_LWP;

  hipLaunchKernelGGL(prep_kernel, dim3(2721), dim3(256), 0, stream,
                     x, dw1, bn11, pw1, bn12, t1, dw2, bn21, pw2, bn22, t2,
                     kvw, wtp, qw, qwp2, lw, lwp);
  hipLaunchKernelGGL(localkv_kernel, dim3(2176), dim3(256), 0, stream,
                     t1, t2, lwp, lb, wtp, kvb, kt1, vt1, kt2, vt2, x, qwp2, qb, q,
                     rpe, rct1, rct2);
  hipLaunchKernelGGL(attn_kernel, dim3(512), dim3(256), 0, stream,
                     q, kt1, vt1, rct1, kt2, vt2, rct2, out);
}

// Round 10
// 178.569 us; speedup vs baseline: 1.0108x; 1.0108x over previous
//
#include <hip/hip_runtime.h>
#include <hip/hip_bf16.h>
#include <math.h>

#define NB 2
#define NC 256
#define HWIN 4096
#define NN 4096
#define ND 32
#define NHH 4
#define EPSV 1e-5f

typedef short short8 __attribute__((ext_vector_type(8)));
typedef float f32x4 __attribute__((ext_vector_type(4)));
typedef unsigned short u16;
typedef unsigned int u32;

// workspace offsets (float32 units)
#define OFF_T1   0          // 131072  (t1T: [b][s][c], c-contiguous)
#define OFF_T2   262144     // 524288  (t2T: [b][s][c])
#define OFF_Q    1310720    // 524288 (bf16 x 1048576)
#define OFF_KT1  1835008    // 65536
#define OFF_VT1  1900544    // 65536
#define OFF_KT2  1966080    // 262144
#define OFF_VT2  2228224    // 262144
#define OFF_RCT1 2490368    // 40960
#define OFF_RCT2 2531328    // 163840
#define OFF_WT   2695168    // 131072  (kvw packed: wtp[c4][o][4], f32)
#define OFF_QWT  5054464    // 32768   (qw packed: qwp2[c][ocq][4], f32)
#define OFF_LWP  5087232    // 2304    (lw packed: lwp[tap][c], f32)
// end 5089536 floats = 20.4 MB

#define QSCALE 0.2550437314857726f   // 1/sqrt(32) * log2(e)
#define LOG2E  1.4426950408889634f

__device__ __forceinline__ u16 f2bf(float x) {   // f32 -> bf16 RNE
  unsigned u = __float_as_uint(x);
  u += 0x7fffu + ((u >> 16) & 1u);
  return (u16)(u >> 16);
}

__device__ __forceinline__ u32 pk_bf16(float a, float b) {  // packed RNE cvt
  __hip_bfloat162 h = __float22bfloat162_rn(make_float2(a, b));
  u32 r; __builtin_memcpy(&r, &h, 4);
  return r;
}

__device__ __forceinline__ float keysw(float t) {  // Keys cubic, a=-0.5
  t = fabsf(t);
  float w;
  if (t < 1.f)       w = ((1.5f*t - 2.5f)*t)*t + 1.f;
  else if (t < 2.f)  w = ((-0.5f*t + 2.5f)*t - 4.f)*t + 2.f;
  else               w = 0.f;
  return w;
}

// ---------- device bodies ----------
// dwconv stores SPATIAL-MAJOR: tT[b][s][c] (stage-2 loads lane-over-c f32x4).
template<int KS, int STR, int PAD, int OH>
__device__ __forceinline__ void dwconv_body(int idx, const float* __restrict__ x,
    const float* __restrict__ dww, const float* __restrict__ bn1,
    const float* __restrict__ pww, const float* __restrict__ bn2,
    float* __restrict__ tout) {
  const int hw = OH*OH;
  int s = idx % hw; int c = (idx/hw) % NC; int b = idx/(hw*NC);
  int oy = s / OH, ox = s % OH;
  const float* xp = x + (b*NC + c)*HWIN;
  const float* wp = dww + c*KS*KS;
  float acc = 0.f;
  #pragma unroll
  for (int ky = 0; ky < KS; ++ky) {
    int iy = oy*STR - PAD + ky;
    if (iy < 0 || iy >= 64) continue;
    #pragma unroll
    for (int kx = 0; kx < KS; ++kx) {
      int ix = ox*STR - PAD + kx;
      if (ix < 0 || ix >= 64) continue;
      acc += xp[iy*64 + ix] * wp[ky*KS + kx];
    }
  }
  float s1 = bn1[c] * rsqrtf(bn1[3*NC + c] + EPSV);
  float z = (acc - bn1[2*NC + c])*s1 + bn1[NC + c];
  z = fmaxf(z, 0.f);
  float s2 = bn2[c] * rsqrtf(bn2[3*NC + c] + EPSV);
  z = z * (pww[c]*s2) + (bn2[NC + c] - bn2[2*NC + c]*s2);
  tout[((size_t)(b*hw + s))*NC + c] = z;   // transposed store
}

__device__ __forceinline__ void rpe_body(int idx, const float* __restrict__ rpe,
                                         u16* __restrict__ rcT, int L, int ch) {
  int r = idx & 63; int l = (idx >> 6) % L; int b = idx / (64*L);
  float f = ((float)l + 0.5f)*(64.f/(float)L) - 0.5f;
  int i0 = (int)floorf(f) - 1;
  const float* rp = rpe + ((b*2 + ch)*64 + r)*64;
  float v = 0.f, wsum = 0.f;
  #pragma unroll
  for (int j = 0; j < 4; ++j) {
    int i = i0 + j;
    if (i >= 0 && i < 64) {
      float w = keysw(f - (float)i);
      v += w * rp[i]; wsum += w;
    }
  }
  rcT[((size_t)(b*L + l))*80 + 4 + r] = f2bf(v / wsum);
}

// ---------- stage 1: dwconvs (transposed out) + weight repacks ----------
__global__ void __launch_bounds__(256) prep_kernel(
    const float* __restrict__ x,
    const float* __restrict__ dw1, const float* __restrict__ bn11,
    const float* __restrict__ pw1, const float* __restrict__ bn12, float* __restrict__ t1,
    const float* __restrict__ dw2, const float* __restrict__ bn21,
    const float* __restrict__ pw2, const float* __restrict__ bn22, float* __restrict__ t2,
    const float* __restrict__ kvw, float* __restrict__ wtp,
    const float* __restrict__ qw, float* __restrict__ qwp2,
    const float* __restrict__ lw, float* __restrict__ lwp) {
  int blk = blockIdx.x;
  int t = threadIdx.x;
  if (blk < 512) {
    dwconv_body<7,4,3,16>(blk*256 + t, x, dw1, bn11, pw1, bn12, t1);
  } else if (blk < 2560) {
    dwconv_body<5,2,2,32>((blk-512)*256 + t, x, dw2, bn21, pw2, bn22, t2);
  } else if (blk < 2688) {
    // kvw repack: wtp[(c4*512 + o)*4 + j] = kvw[o*256 + c4*4 + j]
    int idx = (blk-2560)*256 + t;          // 0..32767
    float4 vv = *(const float4*)(kvw + (size_t)idx*4);
    int o = idx >> 6, c4 = idx & 63;
    *(float4*)(wtp + ((size_t)(c4*512 + o))*4) = vv;
  } else if (blk < 2720) {
    // qw repack: qwp2[(c*32 + ocq)*4 + r] = qw[(ocq*4 + r)*256 + c]
    int idx = (blk-2688)*256 + t;          // 0..8191
    float4 vv = *(const float4*)(qw + (size_t)idx*4);
    int oc = idx >> 6, c0 = (idx & 63)*4;
    int ocq = oc >> 2, r = oc & 3;
    qwp2[((size_t)((c0+0)*32 + ocq))*4 + r] = vv.x;
    qwp2[((size_t)((c0+1)*32 + ocq))*4 + r] = vv.y;
    qwp2[((size_t)((c0+2)*32 + ocq))*4 + r] = vv.z;
    qwp2[((size_t)((c0+3)*32 + ocq))*4 + r] = vv.w;
  } else {
    // lw repack: lwp[tap*256 + c] = lw[c*9 + tap]
    int c = t;
    #pragma unroll
    for (int tp = 0; tp < 9; ++tp) lwp[tp*256 + c] = lw[c*9 + tp];
  }
}

// ---------- stage 2: fused local 3x3 + kv 1x1 + q 1x1 + rpe resample ----------
__global__ void __launch_bounds__(256) localkv_kernel(
    const float* __restrict__ t1T, const float* __restrict__ t2T,
    const float* __restrict__ lwp, const float* __restrict__ lb,
    const float* __restrict__ wtp, const float* __restrict__ kvb,
    u16* __restrict__ kt1, u16* __restrict__ vt1,
    u16* __restrict__ kt2, u16* __restrict__ vt2,
    const float* __restrict__ x, const float* __restrict__ qwp2,
    const float* __restrict__ qb, u16* __restrict__ q,
    const float* __restrict__ rpe, u16* __restrict__ rct1, u16* __restrict__ rct2) {
  __shared__ float sbuf[128*32];   // 16KB
  int blk = blockIdx.x, tid = threadIdx.x;
  if (blk < 640) {
    int kv = blk & 1, ti = blk >> 1;          // 320 tiles of 8 spatial
    const float* tT; u16 *kT, *vT; int OH, hw, b, s0;
    if (ti < 64) { tT = t1T; kT = kt1; vT = vt1; OH = 16; hw = 256;  b = ti >> 5; s0 = (ti & 31)*8; }
    else { int v2 = ti-64; tT = t2T; kT = kt2; vT = vt2; OH = 32; hw = 1024; b = v2 >> 7; s0 = (v2 & 127)*8; }
    int oy = s0 / OH, ox0 = s0 % OH;
    const float* tb = tT + (size_t)b*hw*NC;
    // ---- stage A: 4 channels x 2 spatial per thread, dense f32x4 loads ----
    int cl = tid & 63, spg = tid >> 6;        // 64 c-quads x 4 sp-groups
    int c0 = cl*4;
    f32x4 wt9[9];
    #pragma unroll
    for (int tp = 0; tp < 9; ++tp) wt9[tp] = *(const f32x4*)(lwp + tp*256 + c0);
    f32x4 lb4 = *(const f32x4*)(lb + c0);
    #pragma unroll
    for (int i = 0; i < 2; ++i) {
      int sp = spg*2 + i;
      int ox = ox0 + sp;
      f32x4 a = lb4;
      #pragma unroll
      for (int dy = 0; dy < 3; ++dy) {
        int iy = oy + dy - 1;
        if (iy < 0 || iy >= OH) continue;
        #pragma unroll
        for (int dx = 0; dx < 3; ++dx) {
          int ix = ox + dx - 1;
          if (ix < 0 || ix >= OH) continue;
          f32x4 tv = *(const f32x4*)(tb + (size_t)(iy*OH + ix)*NC + c0);
          a += tv * wt9[dy*3 + dx];
        }
      }
      a += *(const f32x4*)(tb + (size_t)(oy*OH + ox)*NC + c0);   // residual
      *(f32x4*)(sbuf + sp*NC + c0) = a;                          // contiguous
    }
    __syncthreads();
    // ---- stage B: 2 outputs x 4 spatial per thread ----
    int ol = tid & 127, sph = tid >> 7;
    int o0i = kv*256 + ol, o1i = o0i + 128;
    float acc0[4], acc1[4];
    float b0 = kvb[o0i], b1 = kvb[o1i];
    #pragma unroll
    for (int i = 0; i < 4; ++i) { acc0[i] = b0; acc1[i] = b1; }
    #pragma unroll 2
    for (int c4 = 0; c4 < 64; ++c4) {
      f32x4 w0 = *(const f32x4*)(wtp + ((size_t)(c4*512 + o0i))*4);
      f32x4 w1 = *(const f32x4*)(wtp + ((size_t)(c4*512 + o1i))*4);
      #pragma unroll
      for (int i = 0; i < 4; ++i) {
        f32x4 y4 = *(const f32x4*)(sbuf + (sph*4 + i)*NC + c4*4);  // broadcast
        #pragma unroll
        for (int j = 0; j < 4; ++j) { acc0[i] += w0[j]*y4[j]; acc1[i] += w1[j]*y4[j]; }
      }
    }
    int L2 = 2*hw;
    #pragma unroll
    for (int k = 0; k < 2; ++k) {
      const float* ap = k ? acc1 : acc0;
      int oo = ol + k*128;                 // 0..255 within K-or-V half
      int hh = oo >> 6, r = oo & 63, d = r >> 1, e = r & 1;
      if (kv == 0) {
        u16* kp = kT + ((size_t)((b*NHH + hh)*L2 + e*hw + s0 + sph*4))*ND + d;
        #pragma unroll
        for (int j = 0; j < 4; ++j) kp[j*ND] = f2bf(ap[j]);
      } else {
        int l0v = e*hw + s0 + sph*4;
        u16* vp = vT + ((size_t)((b*NHH + hh)*(L2/64) + (l0v >> 6))*ND + d)*64 + (l0v & 63);
        #pragma unroll
        for (int j = 0; j < 4; ++j) vp[j] = f2bf(ap[j]);
      }
    }
  } else if (blk < 896) {
    // ---- q conv: 32 spatial/block, x staged in two 128-channel passes ----
    int qblk = blk - 640;                // 0..255
    int b = qblk >> 7;
    int n0 = (qblk & 127) * 32;
    const float* xb = x + (size_t)b*NC*HWIN + n0;
    int ocq = tid & 31, spg = tid >> 5;  // 32 oc-quads x 8 sp-groups
    float acc[4][4];
    #pragma unroll
    for (int k = 0; k < 4; ++k) {
      float bias = qb[ocq*4 + k];
      #pragma unroll
      for (int i = 0; i < 4; ++i) acc[k][i] = bias;
    }
    #pragma unroll
    for (int half = 0; half < 2; ++half) {
      #pragma unroll
      for (int j = 0; j < 4; ++j) {
        int u = tid + 256*j;             // f32x4 units over [128 c][8 groups]
        int c = u >> 3, spq = u & 7;
        *(f32x4*)(sbuf + c*32 + spq*4) =
            *(const f32x4*)(xb + (size_t)(half*128 + c)*HWIN + spq*4);
      }
      __syncthreads();
      #pragma unroll 4
      for (int c = 0; c < 128; ++c) {
        int cg = half*128 + c;
        f32x4 w4 = *(const f32x4*)(qwp2 + ((size_t)(cg*32 + ocq))*4);  // 4 oc
        f32x4 y4 = *(const f32x4*)(sbuf + c*32 + spg*4);               // 4 sp
        #pragma unroll
        for (int k = 0; k < 4; ++k)
          #pragma unroll
          for (int i = 0; i < 4; ++i) acc[k][i] += w4[k]*y4[i];
      }
      __syncthreads();
    }
    #pragma unroll
    for (int k = 0; k < 4; ++k) {
      int oc = ocq*4 + k;
      int h = oc >> 5, d = oc & 31;
      u16* qp = q + (((size_t)(b*NHH + h))*NN + n0 + spg*4)*ND + d;
      #pragma unroll
      for (int i = 0; i < 4; ++i) qp[i*ND] = f2bf(acc[k][i]*QSCALE);
    }
  } else if (blk < 1152) {
    rpe_body((blk-896)*256 + tid, rpe, rct1, 512, 0);
  } else {
    rpe_body((blk-1152)*256 + tid, rpe, rct2, 2048, 1);
  }
}

// ---------- stage 3: MFMA flash attention, fine-grained blocks ----------
// R9's fold halved block count -> 18% occupancy regression. This version goes
// the other way: 32 q-rows per block (128 threads, 2 waves), separate br1/br2
// blocks. Grid 2048 = 8 blocks/CU (vs R8's 4, R9's 2). Staging: each thread
// handles 2 K-rows + 2 V-rows per tile. LDS 12KB. br2 (32-tile) blocks
// dispatched first. MFMA/softmax/swizzle structure unchanged.
__global__ void __launch_bounds__(128) attn_kernel(
    const u16* __restrict__ qbf,
    const u16* __restrict__ kt1, const u16* __restrict__ vt1, const u16* __restrict__ rct1,
    const u16* __restrict__ kt2, const u16* __restrict__ vt2, const u16* __restrict__ rct2,
    float* __restrict__ out) {
  __shared__ u16 kbuf[64*32];          // K tile, swizzled, 4KB
  __shared__ u16 vbuf[32*64];          // V tile, swizzled, 4KB
  __shared__ u32 pbuf_all[2][16*32];   // per-wave P^T tile, swizzled, 2KB/wave
  int u = blockIdx.x;                  // 2048 blocks; [0,1024) = br2 (long) first
  int br, b, hh, rb;
  if (u < 1024) { br = 1; b = u >> 9; hh = (u >> 7) & 3; rb = u & 127; }
  else { int v = u - 1024; br = 0; b = v >> 9; hh = (v >> 7) & 3; rb = v & 127; }
  const int L  = br ? 2048 : 512;
  const int nt = br ? 32 : 8;
  const u16* kT  = br ? kt2 : kt1;
  const u16* vT  = br ? vt2 : vt1;
  const u16* rcT = br ? rct2 : rct1;
  int tid = threadIdx.x;
  int w = tid >> 6, lane = tid & 63;   // w in {0,1}
  int g = lane >> 4, lo = lane & 15;
  u32* pbuf = pbuf_all[w];
  u16* pbuf16 = (u16*)pbuf;
  int n = rb*32 + w*16 + lo;           // q-row

  const u16* kbase = kT + (size_t)(b*NHH + hh)*L*ND;
  const u16* vbase = vT + (size_t)(b*NHH + hh)*ND*L;   // tiled: [L/64][32][64]

  // Q B-frag (pre-scaled by 1/sqrt(32)*log2e)
  short8 qf = *(const short8*)(qbf + (((size_t)(b*NHH + hh))*NN + n)*ND + 8*g);

  // tap-weight B-frag for RPE ext-MFMA
  float fr = ((float)n + 0.5f)*(1.f/64.f) - 0.5f;
  int ri0 = (int)floorf(fr) - 1;
  int a = ((rb - 1) >> 1) - 1;         // wave-uniform floor(fr(q0)) - 1
  int rmin = a & ~3;
  float wr4[4]; float wsum = 0.f;
  #pragma unroll
  for (int j = 0; j < 4; ++j) {
    int i = ri0 + j;
    float wv = (i >= 0 && i < 64) ? keysw(fr - (float)i) : 0.f;
    wr4[j] = wv; wsum += wv;
  }
  float invw = LOG2E / wsum;
  float wt8[8];
  #pragma unroll
  for (int s = 0; s < 8; ++s) {
    float acc = 0.f;
    #pragma unroll
    for (int j = 0; j < 4; ++j)
      acc += (ri0 + j - rmin == s) ? wr4[j]*invw : 0.f;
    wt8[s] = acc;
  }
  short8 wtf;
  {
    u32 p0 = pk_bf16(wt8[0], wt8[1]), p1 = pk_bf16(wt8[2], wt8[3]);
    u32 p2 = pk_bf16(wt8[4], wt8[5]), p3 = pk_bf16(wt8[6], wt8[7]);
    uint4 uu = make_uint4(p0, p1, p2, p3);
    wtf = __builtin_bit_cast(short8, uu);
    if (g != 0) wtf = (short8)0;
  }
  const u16* rcrow0 = rcT + (size_t)b*L*80 + (rmin + 4);

  const f32x4 zero = {0.f, 0.f, 0.f, 0.f};
  float ssum = 0.f;
  f32x4 o0 = zero, o1 = zero;

  // staging lane roles (128 threads: 2 rows each) + swizzle constants
  int kr_row = tid >> 2, kr_col = (tid & 3)*8;   // K rows kr_row, kr_row+32
  int kr_sw  = ((kr_row >> 1) & 3)*8;            // same for row+32
  int vr_row = tid >> 3, vr_col = (tid & 7)*8;   // V rows vr_row, vr_row+16
  int vr_sw  = (vr_row & 7)*8;                   // same for row+16
  int ksw = ((lo >> 1) & 3)*8;
  int vsw = (lo & 7)*8;
  int psw4 = (lo & 7)*4;
  int psw8 = (lo & 7)*8;

  auto stageLoad = [&](short8& k0, short8& k1, short8& v0, short8& v1, int l0) {
    k0 = *(const short8*)(kbase + (size_t)(l0 + kr_row)*ND + kr_col);
    k1 = *(const short8*)(kbase + (size_t)(l0 + kr_row + 32)*ND + kr_col);
    const u16* vt = vbase + (size_t)(l0 >> 6)*(ND*64);
    v0 = *(const short8*)(vt + vr_row*64 + vr_col);
    v1 = *(const short8*)(vt + (vr_row + 16)*64 + vr_col);
  };
  auto stageStore = [&](short8 k0, short8 k1, short8 v0, short8 v1) {
    *(short8*)(kbuf + kr_row*32 + (kr_col ^ kr_sw)) = k0;
    *(short8*)(kbuf + (kr_row + 32)*32 + (kr_col ^ kr_sw)) = k1;
    *(short8*)(vbuf + vr_row*64 + (vr_col ^ vr_sw)) = v0;
    *(short8*)(vbuf + (vr_row + 16)*64 + (vr_col ^ vr_sw)) = v1;
  };
  auto loadRC = [&](uint4 (&rc)[4], int l0) {
    #pragma unroll
    for (int c = 0; c < 4; ++c) {
      const u16* arow = rcrow0 + (size_t)(l0 + 16*c + lo)*80;
      uint2 ra = *(const uint2*)arow;
      uint2 rb2 = *(const uint2*)(arow + 4);
      rc[c] = make_uint4(ra.x, ra.y, rb2.x, rb2.y);
    }
  };

  short8 k0r, k1r, v0r, v1r;
  uint4 rcA[4], rcB[4];
  stageLoad(k0r, k1r, v0r, v1r, 0);
  loadRC(rcA, 0);

  for (int t = 0; t < nt; ++t) {
    stageStore(k0r, k1r, v0r, v1r);
    __syncthreads();
    if (t < nt-1) { stageLoad(k0r, k1r, v0r, v1r, (t+1)*64); loadRC(rcB, (t+1)*64); }
    f32x4 s4[4];
    #pragma unroll
    for (int c = 0; c < 4; ++c) {
      short8 rcf = __builtin_bit_cast(short8, rcA[c]);
      f32x4 accr = __builtin_amdgcn_mfma_f32_16x16x32_bf16(rcf, wtf, zero, 0, 0, 0);
      short8 kf = *(const short8*)(kbuf + (16*c + lo)*32 + ((8*g) ^ ksw));
      s4[c] = __builtin_amdgcn_mfma_f32_16x16x32_bf16(kf, qf, accr, 0, 0, 0);
    }
    float psum = 0.f;
    u32 pk[8];
    #pragma unroll
    for (int c = 0; c < 4; ++c) {
      float p0 = __builtin_amdgcn_exp2f(s4[c][0]);
      float p1 = __builtin_amdgcn_exp2f(s4[c][1]);
      float p2 = __builtin_amdgcn_exp2f(s4[c][2]);
      float p3 = __builtin_amdgcn_exp2f(s4[c][3]);
      psum += (p0 + p1) + (p2 + p3);
      pk[2*c]   = pk_bf16(p0, p1);
      pk[2*c+1] = pk_bf16(p2, p3);
    }
    ssum += psum;
    #pragma unroll
    for (int c = 0; c < 4; ++c)
      *(uint2*)(pbuf + lo*32 + ((8*c + 2*g) ^ psw4)) = make_uint2(pk[2*c], pk[2*c+1]);
    short8 pf0 = *(const short8*)(pbuf16 + lo*64 + ((8*g) ^ psw8));
    short8 pf1 = *(const short8*)(pbuf16 + lo*64 + ((32 + 8*g) ^ psw8));
    short8 v00 = *(const short8*)(vbuf + lo*64 + ((8*g) ^ vsw));
    short8 v01 = *(const short8*)(vbuf + lo*64 + ((32 + 8*g) ^ vsw));
    short8 v10 = *(const short8*)(vbuf + (16 + lo)*64 + ((8*g) ^ vsw));
    short8 v11 = *(const short8*)(vbuf + (16 + lo)*64 + ((32 + 8*g) ^ vsw));
    o0 = __builtin_amdgcn_mfma_f32_16x16x32_bf16(v00, pf0, o0, 0, 0, 0);
    o1 = __builtin_amdgcn_mfma_f32_16x16x32_bf16(v10, pf0, o1, 0, 0, 0);
    o0 = __builtin_amdgcn_mfma_f32_16x16x32_bf16(v01, pf1, o0, 0, 0, 0);
    o1 = __builtin_amdgcn_mfma_f32_16x16x32_bf16(v11, pf1, o1, 0, 0, 0);
    if (t < nt-1) {
      #pragma unroll
      for (int j = 0; j < 4; ++j) rcA[j] = rcB[j];
    }
    __syncthreads();   // all reads done before next tile's store
  }

  ssum += __shfl_xor(ssum, 16, 64);
  ssum += __shfl_xor(ssum, 32, 64);
  float inv = 1.f/ssum;
  f32x4 w0 = o0*inv, w1 = o1*inv;
  // n = (rb>>1)*64 + (rb&1)*32 + w*16 + lo; br0 -> d-cols 0..31, br1 -> 32..63
  float* op = out + ((size_t)((b*NC + hh*64 + (rb >> 1))*64 +
                              ((rb & 1)*32 + w*16 + lo)))*64 + (br ? 32 : 0);
  *(f32x4*)(op + 4*g)      = w0;
  *(f32x4*)(op + 16 + 4*g) = w1;
}

extern "C" void kernel_launch(void* const* d_in, const int* in_sizes, int n_in,
                              void* d_out, int out_size, void* d_ws, size_t ws_size,
                              hipStream_t stream) {
  const float* x    = (const float*)d_in[0];
  const float* rpe  = (const float*)d_in[1];
  const float* qw   = (const float*)d_in[2];
  const float* qb   = (const float*)d_in[3];
  const float* kvw  = (const float*)d_in[4];
  const float* kvb  = (const float*)d_in[5];
  const float* dw1  = (const float*)d_in[6];
  const float* bn11 = (const float*)d_in[7];
  const float* pw1  = (const float*)d_in[8];
  const float* bn12 = (const float*)d_in[9];
  const float* dw2  = (const float*)d_in[10];
  const float* bn21 = (const float*)d_in[11];
  const float* pw2  = (const float*)d_in[12];
  const float* bn22 = (const float*)d_in[13];
  const float* lw   = (const float*)d_in[14];
  const float* lb   = (const float*)d_in[15];
  float* out = (float*)d_out;
  float* ws  = (float*)d_ws;

  float* t1   = ws + OFF_T1;
  float* t2   = ws + OFF_T2;
  u16*   q    = (u16*)(ws + OFF_Q);
  u16*   kt1  = (u16*)(ws + OFF_KT1);
  u16*   vt1  = (u16*)(ws + OFF_VT1);
  u16*   kt2  = (u16*)(ws + OFF_KT2);
  u16*   vt2  = (u16*)(ws + OFF_VT2);
  u16*   rct1 = (u16*)(ws + OFF_RCT1);
  u16*   rct2 = (u16*)(ws + OFF_RCT2);
  float* wtp  = ws + OFF_WT;
  float* qwp2 = ws + OFF_QWT;
  float* lwp  = ws + OFF_LWP;

  hipLaunchKernelGGL(prep_kernel, dim3(2721), dim3(256), 0, stream,
                     x, dw1, bn11, pw1, bn12, t1, dw2, bn21, pw2, bn22, t2,
                     kvw, wtp, qw, qwp2, lw, lwp);
  hipLaunchKernelGGL(localkv_kernel, dim3(2176), dim3(256), 0, stream,
                     t1, t2, lwp, lb, wtp, kvb, kt1, vt1, kt2, vt2, x, qwp2, qb, q,
                     rpe, rct1, rct2);
  hipLaunchKernelGGL(attn_kernel, dim3(2048), dim3(128), 0, stream,
                     q, kt1, vt1, rct1, kt2, vt2, rct2, out);
}

// Round 11
// 170.501 us; speedup vs baseline: 1.0586x; 1.0473x over previous
//
#include <hip/hip_runtime.h>
#include <hip/hip_bf16.h>
#include <math.h>

#define NB 2
#define NC 256
#define HWIN 4096
#define NN 4096
#define ND 32
#define NHH 4
#define EPSV 1e-5f

typedef short short8 __attribute__((ext_vector_type(8)));
typedef float f32x4 __attribute__((ext_vector_type(4)));
typedef unsigned short u16;
typedef unsigned int u32;

// workspace offsets (float32 units)
#define OFF_T1   0          // 131072  (t1T: [b][s][c], c-contiguous)
#define OFF_T2   262144     // 524288  (t2T: [b][s][c])
#define OFF_Q    1310720    // 524288 (bf16 x 1048576)
#define OFF_KT1  1835008    // 65536
#define OFF_VT1  1900544    // 65536
#define OFF_KT2  1966080    // 262144
#define OFF_VT2  2228224    // 262144
#define OFF_RCT1 2490368    // 40960
#define OFF_RCT2 2531328    // 163840
#define OFF_WT   2695168    // 131072  (kvw packed: wtp[c4][o][4], f32)
#define OFF_QWT  5054464    // 32768   (qw packed: qwp2[c][ocq][4], f32)
#define OFF_LWP  5087232    // 2304    (lw packed: lwp[tap][c], f32)
// end 5089536 floats = 20.4 MB

#define QSCALE 0.2550437314857726f   // 1/sqrt(32) * log2(e)
#define LOG2E  1.4426950408889634f

__device__ __forceinline__ u16 f2bf(float x) {   // f32 -> bf16 RNE
  unsigned u = __float_as_uint(x);
  u += 0x7fffu + ((u >> 16) & 1u);
  return (u16)(u >> 16);
}

__device__ __forceinline__ u32 pk_bf16(float a, float b) {  // packed RNE cvt
  __hip_bfloat162 h = __float22bfloat162_rn(make_float2(a, b));
  u32 r; __builtin_memcpy(&r, &h, 4);
  return r;
}

__device__ __forceinline__ float keysw(float t) {  // Keys cubic, a=-0.5
  t = fabsf(t);
  float w;
  if (t < 1.f)       w = ((1.5f*t - 2.5f)*t)*t + 1.f;
  else if (t < 2.f)  w = ((-0.5f*t + 2.5f)*t - 4.f)*t + 2.f;
  else               w = 0.f;
  return w;
}

// ---------- device bodies ----------
// dwconv stores SPATIAL-MAJOR: tT[b][s][c] (stage-2 loads lane-over-c f32x4).
template<int KS, int STR, int PAD, int OH>
__device__ __forceinline__ void dwconv_body(int idx, const float* __restrict__ x,
    const float* __restrict__ dww, const float* __restrict__ bn1,
    const float* __restrict__ pww, const float* __restrict__ bn2,
    float* __restrict__ tout) {
  const int hw = OH*OH;
  int s = idx % hw; int c = (idx/hw) % NC; int b = idx/(hw*NC);
  int oy = s / OH, ox = s % OH;
  const float* xp = x + (b*NC + c)*HWIN;
  const float* wp = dww + c*KS*KS;
  float acc = 0.f;
  #pragma unroll
  for (int ky = 0; ky < KS; ++ky) {
    int iy = oy*STR - PAD + ky;
    if (iy < 0 || iy >= 64) continue;
    #pragma unroll
    for (int kx = 0; kx < KS; ++kx) {
      int ix = ox*STR - PAD + kx;
      if (ix < 0 || ix >= 64) continue;
      acc += xp[iy*64 + ix] * wp[ky*KS + kx];
    }
  }
  float s1 = bn1[c] * rsqrtf(bn1[3*NC + c] + EPSV);
  float z = (acc - bn1[2*NC + c])*s1 + bn1[NC + c];
  z = fmaxf(z, 0.f);
  float s2 = bn2[c] * rsqrtf(bn2[3*NC + c] + EPSV);
  z = z * (pww[c]*s2) + (bn2[NC + c] - bn2[2*NC + c]*s2);
  tout[((size_t)(b*hw + s))*NC + c] = z;   // transposed store
}

__device__ __forceinline__ void rpe_body(int idx, const float* __restrict__ rpe,
                                         u16* __restrict__ rcT, int L, int ch) {
  int r = idx & 63; int l = (idx >> 6) % L; int b = idx / (64*L);
  float f = ((float)l + 0.5f)*(64.f/(float)L) - 0.5f;
  int i0 = (int)floorf(f) - 1;
  const float* rp = rpe + ((b*2 + ch)*64 + r)*64;
  float v = 0.f, wsum = 0.f;
  #pragma unroll
  for (int j = 0; j < 4; ++j) {
    int i = i0 + j;
    if (i >= 0 && i < 64) {
      float w = keysw(f - (float)i);
      v += w * rp[i]; wsum += w;
    }
  }
  rcT[((size_t)(b*L + l))*80 + 4 + r] = f2bf(v / wsum);
}

// ---------- stage 1: dwconvs (transposed out) + rpe + weight repacks ----------
__global__ void __launch_bounds__(256) prep_kernel(
    const float* __restrict__ x,
    const float* __restrict__ dw1, const float* __restrict__ bn11,
    const float* __restrict__ pw1, const float* __restrict__ bn12, float* __restrict__ t1,
    const float* __restrict__ dw2, const float* __restrict__ bn21,
    const float* __restrict__ pw2, const float* __restrict__ bn22, float* __restrict__ t2,
    const float* __restrict__ rpe, u16* __restrict__ rct1, u16* __restrict__ rct2,
    const float* __restrict__ kvw, float* __restrict__ wtp,
    const float* __restrict__ qw, float* __restrict__ qwp2,
    const float* __restrict__ lw, float* __restrict__ lwp) {
  int blk = blockIdx.x;
  int t = threadIdx.x;
  if (blk < 512) {
    dwconv_body<7,4,3,16>(blk*256 + t, x, dw1, bn11, pw1, bn12, t1);
  } else if (blk < 2560) {
    dwconv_body<5,2,2,32>((blk-512)*256 + t, x, dw2, bn21, pw2, bn22, t2);
  } else if (blk < 2816) {
    rpe_body((blk-2560)*256 + t, rpe, rct1, 512, 0);
  } else if (blk < 3840) {
    rpe_body((blk-2816)*256 + t, rpe, rct2, 2048, 1);
  } else if (blk < 3968) {
    // kvw repack: wtp[(c4*512 + o)*4 + j] = kvw[o*256 + c4*4 + j]
    int idx = (blk-3840)*256 + t;          // 0..32767
    float4 vv = *(const float4*)(kvw + (size_t)idx*4);
    int o = idx >> 6, c4 = idx & 63;
    *(float4*)(wtp + ((size_t)(c4*512 + o))*4) = vv;
  } else if (blk < 4000) {
    // qw repack: qwp2[(c*32 + ocq)*4 + r] = qw[(ocq*4 + r)*256 + c]
    int idx = (blk-3968)*256 + t;          // 0..8191
    float4 vv = *(const float4*)(qw + (size_t)idx*4);
    int oc = idx >> 6, c0 = (idx & 63)*4;
    int ocq = oc >> 2, r = oc & 3;
    qwp2[((size_t)((c0+0)*32 + ocq))*4 + r] = vv.x;
    qwp2[((size_t)((c0+1)*32 + ocq))*4 + r] = vv.y;
    qwp2[((size_t)((c0+2)*32 + ocq))*4 + r] = vv.z;
    qwp2[((size_t)((c0+3)*32 + ocq))*4 + r] = vv.w;
  } else {
    // lw repack: lwp[tap*256 + c] = lw[c*9 + tap]
    int c = t;
    #pragma unroll
    for (int tp = 0; tp < 9; ++tp) lwp[tp*256 + c] = lw[c*9 + tp];
  }
}

// ---------- stage 2: fused local 3x3 + kv 1x1 (both branches) + q 1x1 ----------
// 256-thr blocks, 16KB LDS.
// [0,640): strip tiles (8 spatial), PAIRED even=K/odd=V (dense tT loads).
// [640,896): q conv, 32 spatial, x staged in TWO 128-channel passes.
__global__ void __launch_bounds__(256) localkv_kernel(
    const float* __restrict__ t1T, const float* __restrict__ t2T,
    const float* __restrict__ lwp, const float* __restrict__ lb,
    const float* __restrict__ wtp, const float* __restrict__ kvb,
    u16* __restrict__ kt1, u16* __restrict__ vt1,
    u16* __restrict__ kt2, u16* __restrict__ vt2,
    const float* __restrict__ x, const float* __restrict__ qwp2,
    const float* __restrict__ qb, u16* __restrict__ q) {
  __shared__ float sbuf[128*32];   // 16KB
  int blk = blockIdx.x, tid = threadIdx.x;
  if (blk < 640) {
    int kv = blk & 1, ti = blk >> 1;          // 320 tiles of 8 spatial
    const float* tT; u16 *kT, *vT; int OH, hw, b, s0;
    if (ti < 64) { tT = t1T; kT = kt1; vT = vt1; OH = 16; hw = 256;  b = ti >> 5; s0 = (ti & 31)*8; }
    else { int v2 = ti-64; tT = t2T; kT = kt2; vT = vt2; OH = 32; hw = 1024; b = v2 >> 7; s0 = (v2 & 127)*8; }
    int oy = s0 / OH, ox0 = s0 % OH;
    const float* tb = tT + (size_t)b*hw*NC;
    // ---- stage A: 4 channels x 2 spatial per thread, dense f32x4 loads ----
    int cl = tid & 63, spg = tid >> 6;        // 64 c-quads x 4 sp-groups
    int c0 = cl*4;
    f32x4 wt9[9];
    #pragma unroll
    for (int tp = 0; tp < 9; ++tp) wt9[tp] = *(const f32x4*)(lwp + tp*256 + c0);
    f32x4 lb4 = *(const f32x4*)(lb + c0);
    #pragma unroll
    for (int i = 0; i < 2; ++i) {
      int sp = spg*2 + i;
      int ox = ox0 + sp;
      f32x4 a = lb4;
      #pragma unroll
      for (int dy = 0; dy < 3; ++dy) {
        int iy = oy + dy - 1;
        if (iy < 0 || iy >= OH) continue;
        #pragma unroll
        for (int dx = 0; dx < 3; ++dx) {
          int ix = ox + dx - 1;
          if (ix < 0 || ix >= OH) continue;
          f32x4 tv = *(const f32x4*)(tb + (size_t)(iy*OH + ix)*NC + c0);
          a += tv * wt9[dy*3 + dx];
        }
      }
      a += *(const f32x4*)(tb + (size_t)(oy*OH + ox)*NC + c0);   // residual
      *(f32x4*)(sbuf + sp*NC + c0) = a;                          // contiguous
    }
    __syncthreads();
    // ---- stage B: 2 outputs x 4 spatial per thread ----
    int ol = tid & 127, sph = tid >> 7;
    int o0i = kv*256 + ol, o1i = o0i + 128;
    float acc0[4], acc1[4];
    float b0 = kvb[o0i], b1 = kvb[o1i];
    #pragma unroll
    for (int i = 0; i < 4; ++i) { acc0[i] = b0; acc1[i] = b1; }
    #pragma unroll 2
    for (int c4 = 0; c4 < 64; ++c4) {
      f32x4 w0 = *(const f32x4*)(wtp + ((size_t)(c4*512 + o0i))*4);
      f32x4 w1 = *(const f32x4*)(wtp + ((size_t)(c4*512 + o1i))*4);
      #pragma unroll
      for (int i = 0; i < 4; ++i) {
        f32x4 y4 = *(const f32x4*)(sbuf + (sph*4 + i)*NC + c4*4);  // broadcast
        #pragma unroll
        for (int j = 0; j < 4; ++j) { acc0[i] += w0[j]*y4[j]; acc1[i] += w1[j]*y4[j]; }
      }
    }
    int L2 = 2*hw;
    #pragma unroll
    for (int k = 0; k < 2; ++k) {
      const float* ap = k ? acc1 : acc0;
      int oo = ol + k*128;                 // 0..255 within K-or-V half
      int hh = oo >> 6, r = oo & 63, d = r >> 1, e = r & 1;
      if (kv == 0) {
        u16* kp = kT + ((size_t)((b*NHH + hh)*L2 + e*hw + s0 + sph*4))*ND + d;
        #pragma unroll
        for (int j = 0; j < 4; ++j) kp[j*ND] = f2bf(ap[j]);
      } else {
        int l0v = e*hw + s0 + sph*4;
        u16* vp = vT + ((size_t)((b*NHH + hh)*(L2/64) + (l0v >> 6))*ND + d)*64 + (l0v & 63);
        #pragma unroll
        for (int j = 0; j < 4; ++j) vp[j] = f2bf(ap[j]);
      }
    }
  } else {
    // ---- q conv: 32 spatial/block, x staged in two 128-channel passes ----
    int qblk = blk - 640;                // 0..255
    int b = qblk >> 7;
    int n0 = (qblk & 127) * 32;
    const float* xb = x + (size_t)b*NC*HWIN + n0;
    int ocq = tid & 31, spg = tid >> 5;  // 32 oc-quads x 8 sp-groups
    float acc[4][4];
    #pragma unroll
    for (int k = 0; k < 4; ++k) {
      float bias = qb[ocq*4 + k];
      #pragma unroll
      for (int i = 0; i < 4; ++i) acc[k][i] = bias;
    }
    #pragma unroll
    for (int half = 0; half < 2; ++half) {
      #pragma unroll
      for (int j = 0; j < 4; ++j) {
        int u = tid + 256*j;             // f32x4 units over [128 c][8 groups]
        int c = u >> 3, spq = u & 7;
        *(f32x4*)(sbuf + c*32 + spq*4) =
            *(const f32x4*)(xb + (size_t)(half*128 + c)*HWIN + spq*4);
      }
      __syncthreads();
      #pragma unroll 4
      for (int c = 0; c < 128; ++c) {
        int cg = half*128 + c;
        f32x4 w4 = *(const f32x4*)(qwp2 + ((size_t)(cg*32 + ocq))*4);  // 4 oc
        f32x4 y4 = *(const f32x4*)(sbuf + c*32 + spg*4);               // 4 sp
        #pragma unroll
        for (int k = 0; k < 4; ++k)
          #pragma unroll
          for (int i = 0; i < 4; ++i) acc[k][i] += w4[k]*y4[i];
      }
      __syncthreads();
    }
    #pragma unroll
    for (int k = 0; k < 4; ++k) {
      int oc = ocq*4 + k;
      int h = oc >> 5, d = oc & 31;
      u16* qp = q + (((size_t)(b*NHH + h))*NN + n0 + spg*4)*ND + d;
      #pragma unroll
      for (int i = 0; i < 4; ++i) qp[i*ND] = f2bf(acc[k][i]*QSCALE);
    }
  }
}

// ---------- stage 3: MFMA flash attention, full-L blocks, direct write ----------
// R8 geometry (1024 blocks x 256 thr, separate br1/br2, br2 first) + two
// internal changes:
//  (1) DOUBLE-BUFFERED kbuf/vbuf -> ONE barrier per tile (was 2): stage loads
//      issue right after the barrier (HBM/L2 latency hides under the whole
//      compute chain), stores land in the other buffer at iteration end.
//      Halves the vmcnt/lgkmcnt barrier drains. LDS 16->24KB (4 blocks/CU ok).
//  (2) s_setprio(1) around the MFMA+softmax cluster (T5; +4-7% attn, m191).
__global__ void __launch_bounds__(256) attn_kernel(
    const u16* __restrict__ qbf,
    const u16* __restrict__ kt1, const u16* __restrict__ vt1, const u16* __restrict__ rct1,
    const u16* __restrict__ kt2, const u16* __restrict__ vt2, const u16* __restrict__ rct2,
    float* __restrict__ out) {
  __shared__ u16 kbuf[2][64*32];       // K tiles, swizzled, 2x4KB
  __shared__ u16 vbuf[2][32*64];       // V tiles, swizzled, 2x4KB
  __shared__ u32 pbuf_all[4][16*32];   // per-wave P^T tile, swizzled, 2KB/wave
  int u = blockIdx.x;
  int br, b, hh, rb;
  if (u < 512) { br = 1; b = u >> 8; hh = (u >> 6) & 3; rb = u & 63; }
  else { int v = u - 512; br = 0; b = v >> 8; hh = (v >> 6) & 3; rb = v & 63; }
  int L = br ? 2048 : 512;
  int nt = br ? 32 : 8;
  const u16* kT  = br ? kt2 : kt1;
  const u16* vT  = br ? vt2 : vt1;
  const u16* rcT = br ? rct2 : rct1;
  int tid = threadIdx.x;
  int w = tid >> 6, lane = tid & 63;
  int g = lane >> 4, lo = lane & 15;
  u32* pbuf = pbuf_all[w];
  u16* pbuf16 = (u16*)pbuf;
  int n = rb*64 + w*16 + lo;

  const u16* kbase = kT + (size_t)(b*NHH + hh)*L*ND;
  const u16* vbase = vT + (size_t)(b*NHH + hh)*ND*L;   // tiled: [L/64][32][64]
  const u16* rcTb  = rcT + (size_t)b*L*80;

  short8 qf = *(const short8*)(qbf + (((size_t)(b*NHH + hh))*NN + n)*ND + 8*g);

  float fr = ((float)n + 0.5f)*(1.f/64.f) - 0.5f;
  int ri0 = (int)floorf(fr) - 1;
  int a = (w < 2) ? rb - 2 : rb - 1;     // wave-uniform floor(fr(q0)) - 1
  int rmin = a & ~3;
  float wr4[4]; float wsum = 0.f;
  #pragma unroll
  for (int j = 0; j < 4; ++j) {
    int i = ri0 + j;
    float wv = (i >= 0 && i < 64) ? keysw(fr - (float)i) : 0.f;
    wr4[j] = wv; wsum += wv;
  }
  float invw = LOG2E / wsum;
  float wt8[8];
  #pragma unroll
  for (int s = 0; s < 8; ++s) {
    float acc = 0.f;
    #pragma unroll
    for (int j = 0; j < 4; ++j)
      acc += (ri0 + j - rmin == s) ? wr4[j]*invw : 0.f;
    wt8[s] = acc;
  }
  short8 wtf;
  {
    u32 p0 = pk_bf16(wt8[0], wt8[1]), p1 = pk_bf16(wt8[2], wt8[3]);
    u32 p2 = pk_bf16(wt8[4], wt8[5]), p3 = pk_bf16(wt8[6], wt8[7]);
    uint4 uu = make_uint4(p0, p1, p2, p3);
    wtf = __builtin_bit_cast(short8, uu);
    if (g != 0) wtf = (short8)0;
  }
  const u16* rcrow0 = rcTb + (rmin + 4);

  const f32x4 zero = {0.f, 0.f, 0.f, 0.f};
  float ssum = 0.f;
  f32x4 o0 = zero, o1 = zero;

  // staging lane roles + swizzle constants
  int kr_row = tid >> 2, kr_col = (tid & 3)*8;   // K: 64 rows x 32 u16
  int kr_sw  = ((kr_row >> 1) & 3)*8;
  int vr_row = tid >> 3, vr_col = (tid & 7)*8;   // V: 32 rows x 64 u16
  int vr_sw  = (vr_row & 7)*8;
  int ksw = ((lo >> 1) & 3)*8;
  int vsw = (lo & 7)*8;
  int psw4 = (lo & 7)*4;
  int psw8 = (lo & 7)*8;

  auto stageLoad = [&](short8& kr, short8& vr, int l0) {
    kr = *(const short8*)(kbase + (size_t)(l0 + kr_row)*ND + kr_col);
    vr = *(const short8*)(vbase + (size_t)(l0 >> 6)*(ND*64) + vr_row*64 + vr_col);
  };
  auto stageStore = [&](int bi, short8 kr, short8 vr) {
    *(short8*)(kbuf[bi] + kr_row*32 + (kr_col ^ kr_sw)) = kr;
    *(short8*)(vbuf[bi] + vr_row*64 + (vr_col ^ vr_sw)) = vr;
  };
  auto loadRC = [&](uint4 (&rc)[4], int l0) {
    #pragma unroll
    for (int c = 0; c < 4; ++c) {
      const u16* arow = rcrow0 + (size_t)(l0 + 16*c + lo)*80;
      uint2 ra = *(const uint2*)arow;
      uint2 rb2 = *(const uint2*)(arow + 4);
      rc[c] = make_uint4(ra.x, ra.y, rb2.x, rb2.y);
    }
  };

  short8 kr, vr;
  uint4 rcA[4], rcB[4];
  stageLoad(kr, vr, 0);
  loadRC(rcA, 0);
  stageStore(0, kr, vr);

  for (int t = 0; t < nt; ++t) {
    __syncthreads();                       // buf[t&1] ready for all waves
    int cur = t & 1;
    const u16* kb = kbuf[cur];
    const u16* vb = vbuf[cur];
    if (t < nt-1) { stageLoad(kr, vr, (t+1)*64); loadRC(rcB, (t+1)*64); }
    __builtin_amdgcn_s_setprio(1);
    // S tiles: rc ext-MFMA chained into K.Q MFMA
    f32x4 s4[4];
    #pragma unroll
    for (int c = 0; c < 4; ++c) {
      short8 rcf = __builtin_bit_cast(short8, rcA[c]);
      f32x4 accr = __builtin_amdgcn_mfma_f32_16x16x32_bf16(rcf, wtf, zero, 0, 0, 0);
      short8 kf = *(const short8*)(kb + (16*c + lo)*32 + ((8*g) ^ ksw));
      s4[c] = __builtin_amdgcn_mfma_f32_16x16x32_bf16(kf, qf, accr, 0, 0, 0);
    }
    // max-free softmax: p = exp2(s), raw v_exp_f32
    float psum = 0.f;
    u32 pk[8];
    #pragma unroll
    for (int c = 0; c < 4; ++c) {
      float p0 = __builtin_amdgcn_exp2f(s4[c][0]);
      float p1 = __builtin_amdgcn_exp2f(s4[c][1]);
      float p2 = __builtin_amdgcn_exp2f(s4[c][2]);
      float p3 = __builtin_amdgcn_exp2f(s4[c][3]);
      psum += (p0 + p1) + (p2 + p3);
      pk[2*c]   = pk_bf16(p0, p1);
      pk[2*c+1] = pk_bf16(p2, p3);
    }
    ssum += psum;
    #pragma unroll
    for (int c = 0; c < 4; ++c)
      *(uint2*)(pbuf + lo*32 + ((8*c + 2*g) ^ psw4)) = make_uint2(pk[2*c], pk[2*c+1]);
    short8 pf0 = *(const short8*)(pbuf16 + lo*64 + ((8*g) ^ psw8));
    short8 pf1 = *(const short8*)(pbuf16 + lo*64 + ((32 + 8*g) ^ psw8));
    short8 v00 = *(const short8*)(vb + lo*64 + ((8*g) ^ vsw));
    short8 v01 = *(const short8*)(vb + lo*64 + ((32 + 8*g) ^ vsw));
    short8 v10 = *(const short8*)(vb + (16 + lo)*64 + ((8*g) ^ vsw));
    short8 v11 = *(const short8*)(vb + (16 + lo)*64 + ((32 + 8*g) ^ vsw));
    o0 = __builtin_amdgcn_mfma_f32_16x16x32_bf16(v00, pf0, o0, 0, 0, 0);
    o1 = __builtin_amdgcn_mfma_f32_16x16x32_bf16(v10, pf0, o1, 0, 0, 0);
    o0 = __builtin_amdgcn_mfma_f32_16x16x32_bf16(v01, pf1, o0, 0, 0, 0);
    o1 = __builtin_amdgcn_mfma_f32_16x16x32_bf16(v11, pf1, o1, 0, 0, 0);
    __builtin_amdgcn_s_setprio(0);
    if (t < nt-1) {
      stageStore(cur ^ 1, kr, vr);         // other buffer: no race with readers
      #pragma unroll
      for (int j = 0; j < 4; ++j) rcA[j] = rcB[j];
    }
  }

  ssum += __shfl_xor(ssum, 16, 64);
  ssum += __shfl_xor(ssum, 32, 64);
  float inv = 1.f/ssum;
  f32x4 w0 = o0*inv, w1 = o1*inv;
  // br=0 writes d-cols 0..31; br=1 writes 32..63 (concat along last dim)
  float* op = out + ((size_t)((b*NC + hh*64 + rb)*64 + (w*16 + lo)))*64 + (br ? 32 : 0);
  *(f32x4*)(op + 4*g)      = w0;
  *(f32x4*)(op + 16 + 4*g) = w1;
}

extern "C" void kernel_launch(void* const* d_in, const int* in_sizes, int n_in,
                              void* d_out, int out_size, void* d_ws, size_t ws_size,
                              hipStream_t stream) {
  const float* x    = (const float*)d_in[0];
  const float* rpe  = (const float*)d_in[1];
  const float* qw   = (const float*)d_in[2];
  const float* qb   = (const float*)d_in[3];
  const float* kvw  = (const float*)d_in[4];
  const float* kvb  = (const float*)d_in[5];
  const float* dw1  = (const float*)d_in[6];
  const float* bn11 = (const float*)d_in[7];
  const float* pw1  = (const float*)d_in[8];
  const float* bn12 = (const float*)d_in[9];
  const float* dw2  = (const float*)d_in[10];
  const float* bn21 = (const float*)d_in[11];
  const float* pw2  = (const float*)d_in[12];
  const float* bn22 = (const float*)d_in[13];
  const float* lw   = (const float*)d_in[14];
  const float* lb   = (const float*)d_in[15];
  float* out = (float*)d_out;
  float* ws  = (float*)d_ws;

  float* t1   = ws + OFF_T1;
  float* t2   = ws + OFF_T2;
  u16*   q    = (u16*)(ws + OFF_Q);
  u16*   kt1  = (u16*)(ws + OFF_KT1);
  u16*   vt1  = (u16*)(ws + OFF_VT1);
  u16*   kt2  = (u16*)(ws + OFF_KT2);
  u16*   vt2  = (u16*)(ws + OFF_VT2);
  u16*   rct1 = (u16*)(ws + OFF_RCT1);
  u16*   rct2 = (u16*)(ws + OFF_RCT2);
  float* wtp  = ws + OFF_WT;
  float* qwp2 = ws + OFF_QWT;
  float* lwp  = ws + OFF_LWP;

  hipLaunchKernelGGL(prep_kernel, dim3(4001), dim3(256), 0, stream,
                     x, dw1, bn11, pw1, bn12, t1, dw2, bn21, pw2, bn22, t2,
                     rpe, rct1, rct2, kvw, wtp, qw, qwp2, lw, lwp);
  hipLaunchKernelGGL(localkv_kernel, dim3(896), dim3(256), 0, stream,
                     t1, t2, lwp, lb, wtp, kvb, kt1, vt1, kt2, vt2, x, qwp2, qb, q);
  hipLaunchKernelGGL(attn_kernel, dim3(1024), dim3(256), 0, stream,
                     q, kt1, vt1, rct1, kt2, vt2, rct2, out);
}